// Round 14
// baseline (91.041 us; speedup 1.0000x reference)
//
#include <hip/hip_runtime.h>

// GRNN — fp8(e4m3) MFMA, 8-phase schedule. INSTRUMENTATION ROUND:
// REP=4 on main, REP=8 on prep (idempotent repeats) to surface both above
// the ~40us harness poison-fills in rocprof top-5. Functionally identical
// to R13 (passed, absmax 0.0); REP stripped next round.

#define N_Q 4096
#define N_T 8192
#define DIM 256
#define QB 256
#define TB 256
#define BK 64
#define NKT (DIM / BK)            // 4 K-tiles
#define TILE_B (256 * BK)         // 16384 B per (256-row, 64-k) fp8 tile
#define NC (N_T / TB)             // 32 partial slices
#define NXB (N_T / TB)            // 32
#define NYB (N_Q / QB)            // 16
#define REPM 4
#define REPP 8
#define K1f (-18.033688011112042f)   // -12.5 * log2(e)
#define K2f ( 36.067376022224084f)   //  25.0 * log2(e)

typedef __attribute__((ext_vector_type(4))) float f32x4;
typedef unsigned long long u64;

__device__ __forceinline__ void gload16(const void* g, void* l) {
    __builtin_amdgcn_global_load_lds(
        (const __attribute__((address_space(1))) unsigned*)g,
        (__attribute__((address_space(3))) unsigned*)l, 16, 0, 0);
}

// fp32 -> fp8 e4m3fn (truncating). Layout [s:1][e:4][m:3] -> s|(e<<3)|m.
__device__ __forceinline__ unsigned char f8cvt(float f) {
    unsigned u = __builtin_bit_cast(unsigned, f);
    int e = (int)((u >> 23) & 0xFF) - 120;   // e4m3 biased exponent (bias 7)
    unsigned m = (u >> 20) & 7;
    unsigned s = (u >> 24) & 0x80;
    if (e <= 0) return (unsigned char)s;     // flush small to 0
    if (e > 15) { e = 15; m = 6; }           // clamp to 448 (15,7 is NaN)
    return (unsigned char)(s | ((unsigned)e << 3) | m);
}

#define WVM4() asm volatile("s_waitcnt vmcnt(4)" ::: "memory")
#define WVM0() asm volatile("s_waitcnt vmcnt(0)" ::: "memory")
#define WLG0() asm volatile("s_waitcnt lgkmcnt(0)" ::: "memory")
#define BARX() __builtin_amdgcn_s_barrier()
#define SFEN() __builtin_amdgcn_sched_barrier(0)

// ---- prep: train-row norms (exact fp32, prescaled by K1) + fp8 tiled copies
__global__ __launch_bounds__(256) void grnn_prep(
    const float* __restrict__ X, const float* __restrict__ XT,
    float* __restrict__ xt2s,
    unsigned char* __restrict__ Xb, unsigned char* __restrict__ XTb)
{
    int wave = blockIdx.x * 4 + (threadIdx.x >> 6);
    int lane = threadIdx.x & 63;
    if (wave >= N_Q + N_T) return;
    const float* src; unsigned char* tdst; int row; bool train;
    if (wave < N_Q) { row = wave;       src = X  + (size_t)row * DIM; tdst = Xb;  train = false; }
    else            { row = wave - N_Q; src = XT + (size_t)row * DIM; tdst = XTb; train = true; }

    #pragma unroll 1
    for (int rep = 0; rep < REPP; ++rep) {   // idempotent (instrumentation)
        float4 v = ((const float4*)src)[lane];   // k = 4*lane .. +3

        int kt   = lane >> 4;            // k-tile 0..3
        int kl   = (lane & 15) * 4;      // k within tile 0..60
        int slot = kl >> 3;              // 8B slot 0..7
        int rl   = row & 255;
        int sswz = slot ^ (rl & 7);
        size_t byte = (size_t)((row >> 8) * NKT + kt) * TILE_B
                    + (size_t)rl * 64 + (sswz << 3) + (kl & 7);
        uchar4 b4;
        b4.x = f8cvt(v.x); b4.y = f8cvt(v.y); b4.z = f8cvt(v.z); b4.w = f8cvt(v.w);
        *(uchar4*)(tdst + byte) = b4;

        if (train) {
            float s = v.x*v.x + v.y*v.y + v.z*v.z + v.w*v.w;
            #pragma unroll
            for (int off = 32; off > 0; off >>= 1) s += __shfl_xor(s, off);
            if (lane == 0) xt2s[row] = K1f * s;
        }
    }
}

// ---- main: 256x256 tile, 8 waves, 8-phase schedule, fp8 MFMA ---------------
__global__ __launch_bounds__(512, 2) void grnn_mfma6(
    const unsigned char* __restrict__ Xb, const unsigned char* __restrict__ XTb,
    const float* __restrict__ y, const float* __restrict__ xt2s,
    float* __restrict__ pnum, float* __restrict__ pden)
{
    __shared__ char lds[2][2][TILE_B];   // [buf][A=query / B=train] = 64 KB

    const int bid = blockIdx.x;
    const int xcd = bid & 7;
    const int idx = bid >> 3;            // 0..63
    const int bx  = xcd * 4 + (idx & 3); // 0..31
    const int by  = idx >> 2;            // 0..15

    const int t    = threadIdx.x;
    const int lane = t & 63;
    const int wid  = t >> 6;             // 0..7
    const int wm   = wid >> 2;           // 0..1  (m half: 128 query rows)
    const int wn   = wid & 3;            // 0..3  (n quarter: 64 train rows)
    const int qb   = by * QB;
    const int tb   = bx * TB;
    const int fr   = lane & 15;
    const int fq   = lane >> 4;
    const int swz  = fr & 7;             // row&7 for every frag row

    const char* gA = (const char*)Xb  + (size_t)(by * NKT) * TILE_B;
    const char* gB = (const char*)XTb + (size_t)(bx * NKT) * TILE_B;

    int arow[8], brow[4];
    #pragma unroll
    for (int f = 0; f < 8; ++f) arow[f] = wm * 128 + f * 16 + fr;
    #pragma unroll
    for (int f = 0; f < 4; ++f) brow[f] = wn * 64 + f * 16 + fr;

    // stage one half-tile (128 rows, 8 KB): exactly 1 gload16 per thread
    #define STAGE_H(buf, kt, mat, h) do {                                      \
        const char* g_ = ((mat) ? gB : gA) + (size_t)(kt) * TILE_B             \
                       + (h) * 8192 + t * 16;                                  \
        gload16(g_, &lds[buf][mat][(h) * 8192 + t * 16]);                      \
    } while (0)

    #define READ_B(buf) do {                                                   \
        _Pragma("unroll") for (int nf = 0; nf < 4; ++nf)                       \
        _Pragma("unroll") for (int kk = 0; kk < 2; ++kk)                       \
            bfr[nf][kk] = *(const u64*)&lds[buf][1]                            \
                [brow[nf] * 64 + (((kk * 4 + fq) ^ swz) << 3)];                \
    } while (0)

    #define PHASE(buf, q, DO_B, STG) do {                                      \
        u64 af_[2][2];                                                         \
        _Pragma("unroll") for (int f_ = 0; f_ < 2; ++f_)                       \
        _Pragma("unroll") for (int kk = 0; kk < 2; ++kk)                       \
            af_[f_][kk] = *(const u64*)&lds[buf][0]                            \
                [arow[(q) * 2 + f_] * 64 + (((kk * 4 + fq) ^ swz) << 3)];      \
        if (DO_B) READ_B(buf);                                                 \
        STG;                                                                   \
        BARX();                                                                \
        WLG0(); SFEN();                                                        \
        __builtin_amdgcn_s_setprio(1);                                         \
        _Pragma("unroll") for (int kk = 0; kk < 2; ++kk)                       \
        _Pragma("unroll") for (int f_ = 0; f_ < 2; ++f_)                       \
        _Pragma("unroll") for (int nf = 0; nf < 4; ++nf)                       \
            acc[(q) * 2 + f_][nf] = __builtin_amdgcn_mfma_f32_16x16x32_fp8_fp8(\
                (long)bfr[nf][kk], (long)af_[f_][kk],                          \
                acc[(q) * 2 + f_][nf], 0, 0, 0);                               \
        __builtin_amdgcn_s_setprio(0);                                         \
        BARX();                                                                \
    } while (0)

    #pragma unroll 1
    for (int rep = 0; rep < REPM; ++rep) {   // idempotent (instrumentation)
        f32x4 acc[8][4] = {};
        u64 bfr[4][2];

        // prologue: tile0 -> buf0, tile1 -> buf1 (4 vm-ops each per thread)
        STAGE_H(0, 0, 0, 0); STAGE_H(0, 0, 0, 1); STAGE_H(0, 0, 1, 0); STAGE_H(0, 0, 1, 1);
        STAGE_H(1, 1, 0, 0); STAGE_H(1, 1, 0, 1); STAGE_H(1, 1, 1, 0); STAGE_H(1, 1, 1, 1);
        WVM4(); BARX();                      // tile0 landed

        PHASE(0, 0, 1, ); PHASE(0, 1, 0, ); PHASE(0, 2, 0, ); PHASE(0, 3, 0, );
        WVM0(); BARX();                      // tile1 landed
        PHASE(1, 0, 1, STAGE_H(0, 2, 0, 0));
        PHASE(1, 1, 0, STAGE_H(0, 2, 0, 1));
        PHASE(1, 2, 0, STAGE_H(0, 2, 1, 0));
        PHASE(1, 3, 0, STAGE_H(0, 2, 1, 1));
        WVM0(); BARX();                      // tile2 landed
        PHASE(0, 0, 1, STAGE_H(1, 3, 0, 0));
        PHASE(0, 1, 0, STAGE_H(1, 3, 0, 1));
        PHASE(0, 2, 0, STAGE_H(1, 3, 1, 0));
        PHASE(0, 3, 0, STAGE_H(1, 3, 1, 1));
        WVM0(); BARX();                      // tile3 landed
        PHASE(1, 0, 1, ); PHASE(1, 1, 0, ); PHASE(1, 2, 0, ); PHASE(1, 3, 0, );

        // Epilogue: w' = exp2(K2*c + xt2s[n]); in-lane n-reduce
        float nv[8] = {}, dv[8] = {};
        #pragma unroll
        for (int nf = 0; nf < 4; ++nf)
            #pragma unroll
            for (int rr = 0; rr < 4; ++rr) {
                int n = tb + wn * 64 + nf * 16 + fq * 4 + rr;
                float ts = xt2s[n];
                float yy = y[n];
                #pragma unroll
                for (int mf = 0; mf < 8; ++mf) {
                    float s = fmaf(K2f, acc[mf][nf][rr], ts);
                    float w;
                    asm("v_exp_f32 %0, %1" : "=v"(w) : "v"(s));
                    nv[mf] = fmaf(w, yy, nv[mf]);
                    dv[mf] += w;
                }
            }

        #pragma unroll
        for (int mf = 0; mf < 8; ++mf) {
            nv[mf] += __shfl_xor(nv[mf], 16);
            nv[mf] += __shfl_xor(nv[mf], 32);
            dv[mf] += __shfl_xor(dv[mf], 16);
            dv[mf] += __shfl_xor(dv[mf], 32);
        }

        float* comb = (float*)&lds[0][0][0];   // [wn][arr][256 rows] = 8 KB
        if (fq == 0) {
            #pragma unroll
            for (int mf = 0; mf < 8; ++mf) {
                int row = wm * 128 + mf * 16 + fr;
                comb[(wn * 2 + 0) * 256 + row] = nv[mf];
                comb[(wn * 2 + 1) * 256 + row] = dv[mf];
            }
        }
        __syncthreads();
        {
            int row = t & 255;
            int arr = t >> 8;                  // 0..1 (512 threads)
            float s = comb[(0 * 2 + arr) * 256 + row] + comb[(1 * 2 + arr) * 256 + row]
                    + comb[(2 * 2 + arr) * 256 + row] + comb[(3 * 2 + arr) * 256 + row];
            float* dst = arr ? pden : pnum;
            dst[(size_t)(qb + row) * NC + bx] = s;
        }
        __syncthreads();   // all comb reads done before next rep re-stages LDS
    }
    #undef STAGE_H
    #undef READ_B
    #undef PHASE
}

// ---- reduce: one wave per output row, coalesced [m][NC] reads --------------
__global__ __launch_bounds__(256) void grnn_reduce(const float* __restrict__ pnum,
                                                   const float* __restrict__ pden,
                                                   float* __restrict__ out) {
    int wv   = blockIdx.x * 4 + (threadIdx.x >> 6);
    int lane = threadIdx.x & 63;
    float n = 0.f, d = 0.f;
    if (lane < NC) {
        n = pnum[(size_t)wv * NC + lane];
        d = pden[(size_t)wv * NC + lane];
    }
    #pragma unroll
    for (int off = 1; off < 64; off <<= 1) {
        n += __shfl_xor(n, off);
        d += __shfl_xor(d, off);
    }
    if (lane == 0) out[wv] = n / (d + 1e-9f);
}

// ---- fallback path (fp32 atomics; only if ws is tiny) ----------------------
typedef __attribute__((ext_vector_type(8))) short bf16x8;

__global__ void grnn_zero(float* __restrict__ ws) {
    int i = blockIdx.x * 256 + threadIdx.x;
    if (i < 2 * N_Q) ws[i] = 0.0f;
}

__global__ __launch_bounds__(256) void grnn_rowsq(const float* __restrict__ X,
                                                  const float* __restrict__ XT,
                                                  float* __restrict__ xq2,
                                                  float* __restrict__ xt2) {
    int wave = blockIdx.x * 4 + (threadIdx.x >> 6);
    int lane = threadIdx.x & 63;
    if (wave >= N_Q + N_T) return;
    const float* src; float* dst;
    if (wave < N_Q) { src = X + (size_t)wave * DIM;          dst = xq2 + wave; }
    else            { src = XT + (size_t)(wave - N_Q) * DIM; dst = xt2 + (wave - N_Q); }
    float4 v = ((const float4*)src)[lane];
    float s = v.x*v.x + v.y*v.y + v.z*v.z + v.w*v.w;
    #pragma unroll
    for (int off = 32; off > 0; off >>= 1) s += __shfl_xor(s, off);
    if (lane == 0) *dst = s;
}

__device__ __forceinline__ unsigned pk_bf16(float lo, float hi) {
    unsigned a = __builtin_bit_cast(unsigned, lo);
    unsigned b = __builtin_bit_cast(unsigned, hi);
    return (b & 0xFFFF0000u) | (a >> 16);
}

__global__ __launch_bounds__(256, 2) void grnn_mfma_atomic(
    const float* __restrict__ X, const float* __restrict__ XT,
    const float* __restrict__ y, const float* __restrict__ xq2,
    const float* __restrict__ xt2,
    float* __restrict__ num, float* __restrict__ den)
{
    __shared__ char lds[2][2][16384];
    const int t = threadIdx.x, lane = t & 63, wid = t >> 6;
    const int wm = wid >> 1, wn = wid & 1;
    const int qb = blockIdx.y * 128, tb = blockIdx.x * 128;
    const int srow = t >> 3, sslot = t & 7, sswz = sslot ^ (srow & 7);
    const float* Ag = X  + (size_t)(qb + srow) * DIM + sslot * 8;
    const float* Bg = XT + (size_t)(tb + srow) * DIM + sslot * 8;
    float4 ra[4][2], rb[4][2];

    #define LOADT(kt)                                                          \
        _Pragma("unroll")                                                      \
        for (int p = 0; p < 4; ++p) {                                          \
            const float* ga = Ag + (size_t)(p * 32) * DIM + (kt) * 64;         \
            const float* gb = Bg + (size_t)(p * 32) * DIM + (kt) * 64;         \
            ra[p][0] = *(const float4*)ga;  ra[p][1] = *(const float4*)(ga+4); \
            rb[p][0] = *(const float4*)gb;  rb[p][1] = *(const float4*)(gb+4); \
        }
    #define WRITET(buf)                                                        \
        _Pragma("unroll")                                                      \
        for (int p = 0; p < 4; ++p) {                                          \
            int byte = (srow + p * 32) * 128 + (sswz << 4);                    \
            int4 wa, wb;                                                       \
            wa.x = pk_bf16(ra[p][0].x, ra[p][0].y);                            \
            wa.y = pk_bf16(ra[p][0].z, ra[p][0].w);                            \
            wa.z = pk_bf16(ra[p][1].x, ra[p][1].y);                            \
            wa.w = pk_bf16(ra[p][1].z, ra[p][1].w);                            \
            wb.x = pk_bf16(rb[p][0].x, rb[p][0].y);                            \
            wb.y = pk_bf16(rb[p][0].z, rb[p][0].w);                            \
            wb.z = pk_bf16(rb[p][1].x, rb[p][1].y);                            \
            wb.w = pk_bf16(rb[p][1].z, rb[p][1].w);                            \
            *(int4*)&lds[buf][0][byte] = wa;                                   \
            *(int4*)&lds[buf][1][byte] = wb;                                   \
        }

    f32x4 acc[4][4] = {};
    const int fr = lane & 15, fq = lane >> 4;
    int arow[4], brow[4];
    #pragma unroll
    for (int f = 0; f < 4; ++f) { arow[f] = wm*64+f*16+fr; brow[f] = wn*64+f*16+fr; }

    LOADT(0); WRITET(0); __syncthreads();
    for (int kt = 0; kt < 4; ++kt) {
        if (kt + 1 < 4) { LOADT(kt + 1); }
        const int buf = kt & 1;
        #pragma unroll
        for (int kk = 0; kk < 2; ++kk) {
            bf16x8 af[4], bf[4];
            #pragma unroll
            for (int f = 0; f < 4; ++f) {
                int sa = (fq + kk * 4) ^ (arow[f] & 7);
                int sb = (fq + kk * 4) ^ (brow[f] & 7);
                af[f] = *(const bf16x8*)&lds[buf][0][arow[f] * 128 + (sa << 4)];
                bf[f] = *(const bf16x8*)&lds[buf][1][brow[f] * 128 + (sb << 4)];
            }
            #pragma unroll
            for (int mf = 0; mf < 4; ++mf)
                #pragma unroll
                for (int nf = 0; nf < 4; ++nf)
                    acc[mf][nf] = __builtin_amdgcn_mfma_f32_16x16x32_bf16(
                        af[mf], bf[nf], acc[mf][nf], 0, 0, 0);
        }
        if (kt + 1 < 4) { __syncthreads(); WRITET(buf ^ 1); __syncthreads(); }
    }

    float xq[4][4];
    #pragma unroll
    for (int mf = 0; mf < 4; ++mf)
        #pragma unroll
        for (int r = 0; r < 4; ++r)
            xq[mf][r] = xq2[qb + wm * 64 + mf * 16 + fq * 4 + r];
    float nv[4][4] = {}, dv[4][4] = {};
    #pragma unroll
    for (int nf = 0; nf < 4; ++nf) {
        int n = tb + wn * 64 + nf * 16 + fr;
        float t2 = xt2[n], yvv = y[n];
        #pragma unroll
        for (int mf = 0; mf < 4; ++mf)
            #pragma unroll
            for (int r = 0; r < 4; ++r) {
                float d2 = xq[mf][r] + t2 - 2.0f * acc[mf][nf][r];
                float w  = __expf(-12.5f * d2);
                nv[mf][r] += w * yvv; dv[mf][r] += w;
            }
    }
    #pragma unroll
    for (int off = 1; off < 16; off <<= 1)
        #pragma unroll
        for (int mf = 0; mf < 4; ++mf)
            #pragma unroll
            for (int r = 0; r < 4; ++r) {
                nv[mf][r] += __shfl_xor(nv[mf][r], off);
                dv[mf][r] += __shfl_xor(dv[mf][r], off);
            }
    if (fr == 0) {
        #pragma unroll
        for (int mf = 0; mf < 4; ++mf)
            #pragma unroll
            for (int r = 0; r < 4; ++r) {
                int m = qb + wm * 64 + mf * 16 + fq * 4 + r;
                atomicAdd(&num[m], nv[mf][r]);
                atomicAdd(&den[m], dv[mf][r]);
            }
    }
    #undef LOADT
    #undef WRITET
}

__global__ void grnn_final(const float* __restrict__ num,
                           const float* __restrict__ den,
                           float* __restrict__ out) {
    int i = blockIdx.x * 256 + threadIdx.x;
    if (i < N_Q) out[i] = num[i] / (den[i] + 1e-9f);
}

// ---- launch -----------------------------------------------------------------
extern "C" void kernel_launch(void* const* d_in, const int* in_sizes, int n_in,
                              void* d_out, int out_size, void* d_ws, size_t ws_size,
                              hipStream_t stream) {
    const float* X  = (const float*)d_in[0];
    const float* XT = (const float*)d_in[1];
    const float* y  = (const float*)d_in[2];
    float* out = (float*)d_out;
    char*  ws  = (char*)d_ws;

    const size_t off_pnum = 0;                                  // 512 KB
    const size_t off_pden = off_pnum + (size_t)N_Q * NC * 4;    // 512 KB
    const size_t off_xt2  = off_pden + (size_t)N_Q * NC * 4;    // 32 KB
    const size_t off_Xb   = off_xt2  + (size_t)N_T * 4;         // 1 MB fp8
    const size_t off_XTb  = off_Xb   + (size_t)N_Q * DIM;       // 2 MB fp8
    const size_t need     = off_XTb  + (size_t)N_T * DIM;       // ~4.03 MB

    if (ws_size >= need) {
        float* pnum = (float*)(ws + off_pnum);
        float* pden = (float*)(ws + off_pden);
        float* xt2s = (float*)(ws + off_xt2);
        unsigned char* Xb  = (unsigned char*)(ws + off_Xb);
        unsigned char* XTb = (unsigned char*)(ws + off_XTb);
        hipLaunchKernelGGL(grnn_prep, dim3((N_Q + N_T) / 4), dim3(256), 0, stream,
                           X, XT, xt2s, Xb, XTb);
        hipLaunchKernelGGL(grnn_mfma6, dim3(NXB * NYB), dim3(512), 0, stream,
                           Xb, XTb, y, xt2s, pnum, pden);
        hipLaunchKernelGGL(grnn_reduce, dim3(N_Q / 4), dim3(256), 0, stream,
                           pnum, pden, out);
    } else {
        float* num = (float*)ws;
        float* den = num + N_Q;
        float* xq2 = num + 2 * N_Q;
        float* xt2 = num + 3 * N_Q;
        hipLaunchKernelGGL(grnn_zero, dim3((2 * N_Q + 255) / 256), dim3(256), 0, stream,
                           (float*)ws);
        hipLaunchKernelGGL(grnn_rowsq, dim3((N_Q + N_T + 3) / 4), dim3(256), 0, stream,
                           X, XT, xq2, xt2);
        hipLaunchKernelGGL(grnn_mfma_atomic, dim3(N_T / 128, N_Q / 128), dim3(256), 0, stream,
                           X, XT, y, xq2, xt2, num, den);
        hipLaunchKernelGGL(grnn_final, dim3((N_Q + 255) / 256), dim3(256), 0, stream,
                           num, den, out);
    }
}

// Round 15
// 33.091 us; speedup vs baseline: 2.7512x; 2.7512x over previous
//
#include <hip/hip_runtime.h>

// GRNN (Nadaraya-Watson, Gaussian kernel) — fp8(e4m3) MFMA, 8-phase schedule.
// R14 counters: FETCH 5.7MB (L2-hit staging confirmed), MfmaUtil 31%, but
// SQ_LDS_BANK_CONFLICT=4.2M: b64 frag reads were 2 words/bank per
// quarter-wave because slot^(row&7) ignores row bit 3 (fr and fr+8 collide).
// THIS ROUND: swizzle = slot ^ ((row&7)^((row>>3)&1)) on BOTH sides ->
// each quarter-wave b64 read covers all 32 banks exactly once.
// X [4096,256], X_train [8192,256], y_train [8192,1] -> out [4096]

#define N_Q 4096
#define N_T 8192
#define DIM 256
#define QB 256
#define TB 256
#define BK 64
#define NKT (DIM / BK)            // 4 K-tiles
#define TILE_B (256 * BK)         // 16384 B per (256-row, 64-k) fp8 tile
#define NC (N_T / TB)             // 32 partial slices
#define NXB (N_T / TB)            // 32
#define NYB (N_Q / QB)            // 16
#define K1f (-18.033688011112042f)   // -12.5 * log2(e)
#define K2f ( 36.067376022224084f)   //  25.0 * log2(e)

typedef __attribute__((ext_vector_type(4))) float f32x4;
typedef unsigned long long u64;

__device__ __forceinline__ void gload16(const void* g, void* l) {
    __builtin_amdgcn_global_load_lds(
        (const __attribute__((address_space(1))) unsigned*)g,
        (__attribute__((address_space(3))) unsigned*)l, 16, 0, 0);
}

// fp32 -> fp8 e4m3fn (truncating). Layout [s:1][e:4][m:3] -> s|(e<<3)|m.
__device__ __forceinline__ unsigned char f8cvt(float f) {
    unsigned u = __builtin_bit_cast(unsigned, f);
    int e = (int)((u >> 23) & 0xFF) - 120;   // e4m3 biased exponent (bias 7)
    unsigned m = (u >> 20) & 7;
    unsigned s = (u >> 24) & 0x80;
    if (e <= 0) return (unsigned char)s;     // flush small to 0
    if (e > 15) { e = 15; m = 6; }           // clamp to 448 (15,7 is NaN)
    return (unsigned char)(s | ((unsigned)e << 3) | m);
}

#define WVM4() asm volatile("s_waitcnt vmcnt(4)" ::: "memory")
#define WVM0() asm volatile("s_waitcnt vmcnt(0)" ::: "memory")
#define WLG0() asm volatile("s_waitcnt lgkmcnt(0)" ::: "memory")
#define BARX() __builtin_amdgcn_s_barrier()
#define SFEN() __builtin_amdgcn_sched_barrier(0)

// ---- prep: train-row norms (exact fp32, prescaled by K1) + fp8 tiled copies
// byte = tile*16384 + (row&255)*64 + ((slot8 ^ swz2)<<3) + (k&7),
// swz2 = (row&7)^((row>>3)&1) — bit-3 mix makes quarter-wave b64 reads
// cover all 32 banks (conflict-free). Both-sides swizzle (rule #21).
__global__ __launch_bounds__(256) void grnn_prep(
    const float* __restrict__ X, const float* __restrict__ XT,
    float* __restrict__ xt2s,
    unsigned char* __restrict__ Xb, unsigned char* __restrict__ XTb)
{
    int wave = blockIdx.x * 4 + (threadIdx.x >> 6);
    int lane = threadIdx.x & 63;
    if (wave >= N_Q + N_T) return;
    const float* src; unsigned char* tdst; int row; bool train;
    if (wave < N_Q) { row = wave;       src = X  + (size_t)row * DIM; tdst = Xb;  train = false; }
    else            { row = wave - N_Q; src = XT + (size_t)row * DIM; tdst = XTb; train = true; }
    float4 v = ((const float4*)src)[lane];   // k = 4*lane .. +3

    int kt   = lane >> 4;            // k-tile 0..3
    int kl   = (lane & 15) * 4;      // k within tile 0..60
    int slot = kl >> 3;              // 8B slot 0..7
    int rl   = row & 255;
    int swz2 = (rl & 7) ^ ((rl >> 3) & 1);
    int sswz = slot ^ swz2;
    size_t byte = (size_t)((row >> 8) * NKT + kt) * TILE_B
                + (size_t)rl * 64 + (sswz << 3) + (kl & 7);
    uchar4 b4;
    b4.x = f8cvt(v.x); b4.y = f8cvt(v.y); b4.z = f8cvt(v.z); b4.w = f8cvt(v.w);
    *(uchar4*)(tdst + byte) = b4;

    if (train) {
        float s = v.x*v.x + v.y*v.y + v.z*v.z + v.w*v.w;
        #pragma unroll
        for (int off = 32; off > 0; off >>= 1) s += __shfl_xor(s, off);
        if (lane == 0) xt2s[row] = K1f * s;
    }
}

// ---- main: 256x256 tile, 8 waves, 8-phase schedule, fp8 MFMA ---------------
__global__ __launch_bounds__(512, 2) void grnn_mfma6(
    const unsigned char* __restrict__ Xb, const unsigned char* __restrict__ XTb,
    const float* __restrict__ y, const float* __restrict__ xt2s,
    float* __restrict__ pnum, float* __restrict__ pden)
{
    __shared__ char lds[2][2][TILE_B];   // [buf][A=query / B=train] = 64 KB

    const int bid = blockIdx.x;
    const int xcd = bid & 7;
    const int idx = bid >> 3;            // 0..63
    const int bx  = xcd * 4 + (idx & 3); // 0..31
    const int by  = idx >> 2;            // 0..15

    const int t    = threadIdx.x;
    const int lane = t & 63;
    const int wid  = t >> 6;             // 0..7
    const int wm   = wid >> 2;           // 0..1  (m half: 128 query rows)
    const int wn   = wid & 3;            // 0..3  (n quarter: 64 train rows)
    const int qb   = by * QB;
    const int tb   = bx * TB;
    const int fr   = lane & 15;
    const int fq   = lane >> 4;
    // frag rows are wX*base + f*16 + fr, so row&7 = fr&7 and row bit3 = fr
    // bit3 -> per-lane constant swizzle:
    const int swz  = (fr & 7) ^ (fr >> 3);

    const char* gA = (const char*)Xb  + (size_t)(by * NKT) * TILE_B;
    const char* gB = (const char*)XTb + (size_t)(bx * NKT) * TILE_B;

    int arow[8], brow[4];
    #pragma unroll
    for (int f = 0; f < 8; ++f) arow[f] = wm * 128 + f * 16 + fr;
    #pragma unroll
    for (int f = 0; f < 4; ++f) brow[f] = wn * 64 + f * 16 + fr;

    f32x4 acc[8][4] = {};   // acc[mf][nf]: D rows = train n, cols = query m
    u64 bfr[4][2];          // B frags (8 fp8 each), read once per K-tile

    // stage one half-tile (128 rows, 8 KB): exactly 1 gload16 per thread
    #define STAGE_H(buf, kt, mat, h) do {                                      \
        const char* g_ = ((mat) ? gB : gA) + (size_t)(kt) * TILE_B             \
                       + (h) * 8192 + t * 16;                                  \
        gload16(g_, &lds[buf][mat][(h) * 8192 + t * 16]);                      \
    } while (0)

    #define READ_B(buf) do {                                                   \
        _Pragma("unroll") for (int nf = 0; nf < 4; ++nf)                       \
        _Pragma("unroll") for (int kk = 0; kk < 2; ++kk)                       \
            bfr[nf][kk] = *(const u64*)&lds[buf][1]                            \
                [brow[nf] * 64 + (((kk * 4 + fq) ^ swz) << 3)];                \
    } while (0)

    // one phase: 4 A-frag b64 reads (+8 B on q==0) || optional stage ||
    //            barrier || lgkm0 || 16 MFMA || barrier
    #define PHASE(buf, q, DO_B, STG) do {                                      \
        u64 af_[2][2];                                                         \
        _Pragma("unroll") for (int f_ = 0; f_ < 2; ++f_)                       \
        _Pragma("unroll") for (int kk = 0; kk < 2; ++kk)                       \
            af_[f_][kk] = *(const u64*)&lds[buf][0]                            \
                [arow[(q) * 2 + f_] * 64 + (((kk * 4 + fq) ^ swz) << 3)];      \
        if (DO_B) READ_B(buf);                                                 \
        STG;                                                                   \
        BARX();                                                                \
        WLG0(); SFEN();                                                        \
        __builtin_amdgcn_s_setprio(1);                                         \
        _Pragma("unroll") for (int kk = 0; kk < 2; ++kk)                       \
        _Pragma("unroll") for (int f_ = 0; f_ < 2; ++f_)                       \
        _Pragma("unroll") for (int nf = 0; nf < 4; ++nf)                       \
            acc[(q) * 2 + f_][nf] = __builtin_amdgcn_mfma_f32_16x16x32_fp8_fp8(\
                (long)bfr[nf][kk], (long)af_[f_][kk],                          \
                acc[(q) * 2 + f_][nf], 0, 0, 0);                               \
        __builtin_amdgcn_s_setprio(0);                                         \
        BARX();                                                                \
    } while (0)

    // prologue: tile0 -> buf0, tile1 -> buf1 (4 vm-ops each per thread)
    STAGE_H(0, 0, 0, 0); STAGE_H(0, 0, 0, 1); STAGE_H(0, 0, 1, 0); STAGE_H(0, 0, 1, 1);
    STAGE_H(1, 1, 0, 0); STAGE_H(1, 1, 0, 1); STAGE_H(1, 1, 1, 0); STAGE_H(1, 1, 1, 1);
    WVM4(); BARX();                      // tile0 landed (own 4 + barrier => all)

    // K-tile 0 (buf0)
    PHASE(0, 0, 1, ); PHASE(0, 1, 0, ); PHASE(0, 2, 0, ); PHASE(0, 3, 0, );
    WVM0(); BARX();                      // tile1 landed
    // K-tile 1 (buf1) — stage tile2 -> buf0, one half-tile per phase
    PHASE(1, 0, 1, STAGE_H(0, 2, 0, 0));
    PHASE(1, 1, 0, STAGE_H(0, 2, 0, 1));
    PHASE(1, 2, 0, STAGE_H(0, 2, 1, 0));
    PHASE(1, 3, 0, STAGE_H(0, 2, 1, 1));
    WVM0(); BARX();                      // tile2 landed
    // K-tile 2 (buf0) — stage tile3 -> buf1
    PHASE(0, 0, 1, STAGE_H(1, 3, 0, 0));
    PHASE(0, 1, 0, STAGE_H(1, 3, 0, 1));
    PHASE(0, 2, 0, STAGE_H(1, 3, 1, 0));
    PHASE(0, 3, 0, STAGE_H(1, 3, 1, 1));
    WVM0(); BARX();                      // tile3 landed
    // K-tile 3 (buf1)
    PHASE(1, 0, 1, ); PHASE(1, 1, 0, ); PHASE(1, 2, 0, ); PHASE(1, 3, 0, );

    // Epilogue: w' = exp2(K2*c + xt2s[n]); in-lane n-reduce (+2 shfl over fq)
    float nv[8] = {}, dv[8] = {};
    #pragma unroll
    for (int nf = 0; nf < 4; ++nf)
        #pragma unroll
        for (int rr = 0; rr < 4; ++rr) {
            int n = tb + wn * 64 + nf * 16 + fq * 4 + rr;
            float ts = xt2s[n];
            float yy = y[n];
            #pragma unroll
            for (int mf = 0; mf < 8; ++mf) {
                float s = fmaf(K2f, acc[mf][nf][rr], ts);
                float w;
                asm("v_exp_f32 %0, %1" : "=v"(w) : "v"(s));  // 2^s, ->0 underflow
                nv[mf] = fmaf(w, yy, nv[mf]);
                dv[mf] += w;
            }
        }

    #pragma unroll
    for (int mf = 0; mf < 8; ++mf) {
        nv[mf] += __shfl_xor(nv[mf], 16);
        nv[mf] += __shfl_xor(nv[mf], 32);
        dv[mf] += __shfl_xor(dv[mf], 16);
        dv[mf] += __shfl_xor(dv[mf], 32);
    }

    // Cross-wn combine in LDS (overlay buf0; no readers remain), then one
    // slice per block: pnum/pden layout [m][NC].
    float* comb = (float*)&lds[0][0][0];   // [wn][arr][256 rows] = 8 KB
    if (fq == 0) {
        #pragma unroll
        for (int mf = 0; mf < 8; ++mf) {
            int row = wm * 128 + mf * 16 + fr;
            comb[(wn * 2 + 0) * 256 + row] = nv[mf];
            comb[(wn * 2 + 1) * 256 + row] = dv[mf];
        }
    }
    __syncthreads();
    {
        int row = t & 255;
        int arr = t >> 8;                  // 0..1 (512 threads)
        float s = comb[(0 * 2 + arr) * 256 + row] + comb[(1 * 2 + arr) * 256 + row]
                + comb[(2 * 2 + arr) * 256 + row] + comb[(3 * 2 + arr) * 256 + row];
        float* dst = arr ? pden : pnum;
        dst[(size_t)(qb + row) * NC + bx] = s;
    }
    #undef STAGE_H
    #undef READ_B
    #undef PHASE
}

// ---- reduce: one wave per output row, coalesced [m][NC] reads --------------
__global__ __launch_bounds__(256) void grnn_reduce(const float* __restrict__ pnum,
                                                   const float* __restrict__ pden,
                                                   float* __restrict__ out) {
    int wv   = blockIdx.x * 4 + (threadIdx.x >> 6);
    int lane = threadIdx.x & 63;
    float n = 0.f, d = 0.f;
    if (lane < NC) {
        n = pnum[(size_t)wv * NC + lane];
        d = pden[(size_t)wv * NC + lane];
    }
    #pragma unroll
    for (int off = 1; off < 64; off <<= 1) {
        n += __shfl_xor(n, off);
        d += __shfl_xor(d, off);
    }
    if (lane == 0) out[wv] = n / (d + 1e-9f);
}

// ---- fallback path (fp32 atomics; only if ws is tiny) ----------------------
typedef __attribute__((ext_vector_type(8))) short bf16x8;

__global__ void grnn_zero(float* __restrict__ ws) {
    int i = blockIdx.x * 256 + threadIdx.x;
    if (i < 2 * N_Q) ws[i] = 0.0f;
}

__global__ __launch_bounds__(256) void grnn_rowsq(const float* __restrict__ X,
                                                  const float* __restrict__ XT,
                                                  float* __restrict__ xq2,
                                                  float* __restrict__ xt2) {
    int wave = blockIdx.x * 4 + (threadIdx.x >> 6);
    int lane = threadIdx.x & 63;
    if (wave >= N_Q + N_T) return;
    const float* src; float* dst;
    if (wave < N_Q) { src = X + (size_t)wave * DIM;          dst = xq2 + wave; }
    else            { src = XT + (size_t)(wave - N_Q) * DIM; dst = xt2 + (wave - N_Q); }
    float4 v = ((const float4*)src)[lane];
    float s = v.x*v.x + v.y*v.y + v.z*v.z + v.w*v.w;
    #pragma unroll
    for (int off = 32; off > 0; off >>= 1) s += __shfl_xor(s, off);
    if (lane == 0) *dst = s;
}

__device__ __forceinline__ unsigned pk_bf16(float lo, float hi) {
    unsigned a = __builtin_bit_cast(unsigned, lo);
    unsigned b = __builtin_bit_cast(unsigned, hi);
    return (b & 0xFFFF0000u) | (a >> 16);
}

__global__ __launch_bounds__(256, 2) void grnn_mfma_atomic(
    const float* __restrict__ X, const float* __restrict__ XT,
    const float* __restrict__ y, const float* __restrict__ xq2,
    const float* __restrict__ xt2,
    float* __restrict__ num, float* __restrict__ den)
{
    __shared__ char lds[2][2][16384];
    const int t = threadIdx.x, lane = t & 63, wid = t >> 6;
    const int wm = wid >> 1, wn = wid & 1;
    const int qb = blockIdx.y * 128, tb = blockIdx.x * 128;
    const int srow = t >> 3, sslot = t & 7, sswz = sslot ^ (srow & 7);
    const float* Ag = X  + (size_t)(qb + srow) * DIM + sslot * 8;
    const float* Bg = XT + (size_t)(tb + srow) * DIM + sslot * 8;
    float4 ra[4][2], rb[4][2];

    #define LOADT(kt)                                                          \
        _Pragma("unroll")                                                      \
        for (int p = 0; p < 4; ++p) {                                          \
            const float* ga = Ag + (size_t)(p * 32) * DIM + (kt) * 64;         \
            const float* gb = Bg + (size_t)(p * 32) * DIM + (kt) * 64;         \
            ra[p][0] = *(const float4*)ga;  ra[p][1] = *(const float4*)(ga+4); \
            rb[p][0] = *(const float4*)gb;  rb[p][1] = *(const float4*)(gb+4); \
        }
    #define WRITET(buf)                                                        \
        _Pragma("unroll")                                                      \
        for (int p = 0; p < 4; ++p) {                                          \
            int byte = (srow + p * 32) * 128 + (sswz << 4);                    \
            int4 wa, wb;                                                       \
            wa.x = pk_bf16(ra[p][0].x, ra[p][0].y);                            \
            wa.y = pk_bf16(ra[p][0].z, ra[p][0].w);                            \
            wa.z = pk_bf16(ra[p][1].x, ra[p][1].y);                            \
            wa.w = pk_bf16(ra[p][1].z, ra[p][1].w);                            \
            wb.x = pk_bf16(rb[p][0].x, rb[p][0].y);                            \
            wb.y = pk_bf16(rb[p][0].z, rb[p][0].w);                            \
            wb.z = pk_bf16(rb[p][1].x, rb[p][1].y);                            \
            wb.w = pk_bf16(rb[p][1].z, rb[p][1].w);                            \
            *(int4*)&lds[buf][0][byte] = wa;                                   \
            *(int4*)&lds[buf][1][byte] = wb;                                   \
        }

    f32x4 acc[4][4] = {};
    const int fr = lane & 15, fq = lane >> 4;
    int arow[4], brow[4];
    #pragma unroll
    for (int f = 0; f < 4; ++f) { arow[f] = wm*64+f*16+fr; brow[f] = wn*64+f*16+fr; }

    LOADT(0); WRITET(0); __syncthreads();
    for (int kt = 0; kt < 4; ++kt) {
        if (kt + 1 < 4) { LOADT(kt + 1); }
        const int buf = kt & 1;
        #pragma unroll
        for (int kk = 0; kk < 2; ++kk) {
            bf16x8 af[4], bf[4];
            #pragma unroll
            for (int f = 0; f < 4; ++f) {
                int sa = (fq + kk * 4) ^ (arow[f] & 7);
                int sb = (fq + kk * 4) ^ (brow[f] & 7);
                af[f] = *(const bf16x8*)&lds[buf][0][arow[f] * 128 + (sa << 4)];
                bf[f] = *(const bf16x8*)&lds[buf][1][brow[f] * 128 + (sb << 4)];
            }
            #pragma unroll
            for (int mf = 0; mf < 4; ++mf)
                #pragma unroll
                for (int nf = 0; nf < 4; ++nf)
                    acc[mf][nf] = __builtin_amdgcn_mfma_f32_16x16x32_bf16(
                        af[mf], bf[nf], acc[mf][nf], 0, 0, 0);
        }
        if (kt + 1 < 4) { __syncthreads(); WRITET(buf ^ 1); __syncthreads(); }
    }

    float xq[4][4];
    #pragma unroll
    for (int mf = 0; mf < 4; ++mf)
        #pragma unroll
        for (int r = 0; r < 4; ++r)
            xq[mf][r] = xq2[qb + wm * 64 + mf * 16 + fq * 4 + r];
    float nv[4][4] = {}, dv[4][4] = {};
    #pragma unroll
    for (int nf = 0; nf < 4; ++nf) {
        int n = tb + wn * 64 + nf * 16 + fr;
        float t2 = xt2[n], yvv = y[n];
        #pragma unroll
        for (int mf = 0; mf < 4; ++mf)
            #pragma unroll
            for (int r = 0; r < 4; ++r) {
                float d2 = xq[mf][r] + t2 - 2.0f * acc[mf][nf][r];
                float w  = __expf(-12.5f * d2);
                nv[mf][r] += w * yvv; dv[mf][r] += w;
            }
    }
    #pragma unroll
    for (int off = 1; off < 16; off <<= 1)
        #pragma unroll
        for (int mf = 0; mf < 4; ++mf)
            #pragma unroll
            for (int r = 0; r < 4; ++r) {
                nv[mf][r] += __shfl_xor(nv[mf][r], off);
                dv[mf][r] += __shfl_xor(dv[mf][r], off);
            }
    if (fr == 0) {
        #pragma unroll
        for (int mf = 0; mf < 4; ++mf)
            #pragma unroll
            for (int r = 0; r < 4; ++r) {
                int m = qb + wm * 64 + mf * 16 + fq * 4 + r;
                atomicAdd(&num[m], nv[mf][r]);
                atomicAdd(&den[m], dv[mf][r]);
            }
    }
    #undef LOADT
    #undef WRITET
}

__global__ void grnn_final(const float* __restrict__ num,
                           const float* __restrict__ den,
                           float* __restrict__ out) {
    int i = blockIdx.x * 256 + threadIdx.x;
    if (i < N_Q) out[i] = num[i] / (den[i] + 1e-9f);
}

// ---- launch -----------------------------------------------------------------
extern "C" void kernel_launch(void* const* d_in, const int* in_sizes, int n_in,
                              void* d_out, int out_size, void* d_ws, size_t ws_size,
                              hipStream_t stream) {
    const float* X  = (const float*)d_in[0];
    const float* XT = (const float*)d_in[1];
    const float* y  = (const float*)d_in[2];
    float* out = (float*)d_out;
    char*  ws  = (char*)d_ws;

    const size_t off_pnum = 0;                                  // 512 KB
    const size_t off_pden = off_pnum + (size_t)N_Q * NC * 4;    // 512 KB
    const size_t off_xt2  = off_pden + (size_t)N_Q * NC * 4;    // 32 KB
    const size_t off_Xb   = off_xt2  + (size_t)N_T * 4;         // 1 MB fp8
    const size_t off_XTb  = off_Xb   + (size_t)N_Q * DIM;       // 2 MB fp8
    const size_t need     = off_XTb  + (size_t)N_T * DIM;       // ~4.03 MB

    if (ws_size >= need) {
        float* pnum = (float*)(ws + off_pnum);
        float* pden = (float*)(ws + off_pden);
        float* xt2s = (float*)(ws + off_xt2);
        unsigned char* Xb  = (unsigned char*)(ws + off_Xb);
        unsigned char* XTb = (unsigned char*)(ws + off_XTb);
        hipLaunchKernelGGL(grnn_prep, dim3((N_Q + N_T) / 4), dim3(256), 0, stream,
                           X, XT, xt2s, Xb, XTb);
        hipLaunchKernelGGL(grnn_mfma6, dim3(NXB * NYB), dim3(512), 0, stream,
                           Xb, XTb, y, xt2s, pnum, pden);
        hipLaunchKernelGGL(grnn_reduce, dim3(N_Q / 4), dim3(256), 0, stream,
                           pnum, pden, out);
    } else {
        float* num = (float*)ws;
        float* den = num + N_Q;
        float* xq2 = num + 2 * N_Q;
        float* xt2 = num + 3 * N_Q;
        hipLaunchKernelGGL(grnn_zero, dim3((2 * N_Q + 255) / 256), dim3(256), 0, stream,
                           (float*)ws);
        hipLaunchKernelGGL(grnn_rowsq, dim3((N_Q + N_T + 3) / 4), dim3(256), 0, stream,
                           X, XT, xq2, xt2);
        hipLaunchKernelGGL(grnn_mfma_atomic, dim3(N_T / 128, N_Q / 128), dim3(256), 0, stream,
                           X, XT, y, xq2, xt2, num, den);
        hipLaunchKernelGGL(grnn_final, dim3((N_Q + 255) / 256), dim3(256), 0, stream,
                           num, den, out);
    }
}